// Round 13
// baseline (396.212 us; speedup 1.0000x reference)
//
#include <hip/hip_runtime.h>
#include <hip/hip_bf16.h>

#define BB 16
#define NN 4096
#define SS 1024
#define C1 128
#define C2 256
#define CIN 384
#define CO 128

#define KCH 16           // knn S-chunks
#define SCH (SS / KCH)   // 64 points per chunk

typedef __bf16 bf16x8 __attribute__((ext_vector_type(8)));
typedef float f32x4 __attribute__((ext_vector_type(4)));

// ------- Kernel 1a: partial 3-NN scan over one S-chunk ---------------------
// FROZEN ARITHMETIC (see r12/r2 notes): distance expr + insertion chain
// byte-identical; only the loop range is per-chunk. KCH=16 for occupancy.
__global__ __launch_bounds__(256) void knn_part_kernel(
    const float* __restrict__ xyz1, const float* __restrict__ xyz2,
    float4* __restrict__ pd4, int4* __restrict__ pi4)
{
    __shared__ float4 pts[SCH];   // 1 KB
    const int b = blockIdx.z;
    const int ch = blockIdx.y;
    const float* p2 = xyz2 + ((size_t)b * SS + (size_t)ch * SCH) * 3;
    for (int i = threadIdx.x; i < SCH; i += 256) {
        float x = p2[i * 3 + 0], y = p2[i * 3 + 1], z = p2[i * 3 + 2];
        pts[i] = make_float4(x, y, z, x * x + y * y + z * z);
    }
    __syncthreads();

    const int n = blockIdx.x * 256 + threadIdx.x;
    const float* p1 = xyz1 + ((size_t)b * NN + n) * 3;
    const float x = p1[0], y = p1[1], z = p1[2];
    const float s1 = x * x + y * y + z * z;

    float d0 = 3.4e38f, d1 = 3.4e38f, d2 = 3.4e38f, d3 = 3.4e38f;
    int i0 = 0, i1 = 0, i2 = 0, i3 = 0;
    const int sbase = ch * SCH;
    #pragma unroll 4
    for (int sl = 0; sl < SCH; ++sl) {
        float4 p = pts[sl];
        float d = s1 + p.w - 2.0f * (x * p.x + y * p.y + z * p.z);
        int s = sbase + sl;
        bool lt0 = d < d0, lt1 = d < d1, lt2 = d < d2, lt3 = d < d3;
        float nd3 = lt2 ? d2 : (lt3 ? d : d3); int ni3 = lt2 ? i2 : (lt3 ? s : i3);
        float nd2 = lt1 ? d1 : (lt2 ? d : d2); int ni2 = lt1 ? i1 : (lt2 ? s : i2);
        float nd1 = lt0 ? d0 : (lt1 ? d : d1); int ni1 = lt0 ? i0 : (lt1 ? s : i1);
        d0 = lt0 ? d : d0;                     i0 = lt0 ? s : i0;
        d1 = nd1; i1 = ni1; d2 = nd2; i2 = ni2; d3 = nd3; i3 = ni3;
    }
    size_t o = ((size_t)b * NN + n) * KCH + ch;
    pd4[o] = make_float4(d0, d1, d2, d3);
    pi4[o] = make_int4(i0, i1, i2, i3);
}

// ------- Kernel 1b: merge per-chunk top-4 -> global top-4 + weights --------
// Identical strict-< insertion chain; candidates arrive in (chunk, asc-d)
// order which preserves the sequential scan's (d, s) tie ordering.
__global__ __launch_bounds__(256) void knn_merge_kernel(
    const float4* __restrict__ pd4, const int4* __restrict__ pi4,
    int* __restrict__ idx4, float* __restrict__ w4)
{
    const int n = blockIdx.x * 256 + threadIdx.x;
    const int b = blockIdx.y;
    const size_t o = ((size_t)b * NN + n) * KCH;

    float d0 = 3.4e38f, d1 = 3.4e38f, d2 = 3.4e38f, d3 = 3.4e38f;
    int i0 = 0, i1 = 0, i2 = 0, i3 = 0;
    #pragma unroll
    for (int ch = 0; ch < KCH; ++ch) {
        float4 pd = pd4[o + ch];
        int4 pi = pi4[o + ch];
        float cd[4] = { pd.x, pd.y, pd.z, pd.w };
        int   ci[4] = { pi.x, pi.y, pi.z, pi.w };
        #pragma unroll
        for (int k = 0; k < 4; ++k) {
            float d = cd[k]; int s = ci[k];
            bool lt0 = d < d0, lt1 = d < d1, lt2 = d < d2, lt3 = d < d3;
            float nd3 = lt2 ? d2 : (lt3 ? d : d3); int ni3 = lt2 ? i2 : (lt3 ? s : i3);
            float nd2 = lt1 ? d1 : (lt2 ? d : d2); int ni2 = lt1 ? i1 : (lt2 ? s : i2);
            float nd1 = lt0 ? d0 : (lt1 ? d : d1); int ni1 = lt0 ? i0 : (lt1 ? s : i1);
            d0 = lt0 ? d : d0;                     i0 = lt0 ? s : i0;
            d1 = nd1; i1 = ni1; d2 = nd2; i2 = ni2; d3 = nd3; i3 = ni3;
        }
    }
    float r0 = 1.0f / (d0 + 1e-8f);
    float r1 = 1.0f / (d1 + 1e-8f);
    float r2 = 1.0f / (d2 + 1e-8f);
    float rs = r0 + r1 + r2;
    bool tie = (d2 == d3);
    size_t base = ((size_t)b * NN + n) * 4;
    idx4[base + 0] = i0; idx4[base + 1] = i1;
    idx4[base + 2] = i2; idx4[base + 3] = i3;
    w4[base + 0] = r0 / rs; w4[base + 1] = r1 / rs;
    w4[base + 2] = r2 / rs; w4[base + 3] = tie ? -1.0f : 0.0f;
}

// ---------------- Kernel 2: transpose points2 f32[C2,S] -> f32[S,C2] -------
__global__ __launch_bounds__(256) void p2t_kernel(
    const float* __restrict__ p2, float* __restrict__ p2t)
{
    __shared__ float tile[64][65];
    const int b = blockIdx.z;
    const int s0 = blockIdx.x * 64, c0 = blockIdx.y * 64;
    for (int i = threadIdx.x; i < 64 * 64; i += 256) {
        int s = i & 63, c = i >> 6;
        tile[c][s] = p2[((size_t)b * C2 + c0 + c) * SS + s0 + s];
    }
    __syncthreads();
    for (int i = threadIdx.x; i < 64 * 64; i += 256) {
        int c = i & 63, s = i >> 6;
        p2t[((size_t)b * SS + s0 + s) * C2 + c0 + c] = tile[c][s];
    }
}

// ------- Kernel 2c: split conv weights f32 -> bf16 hi/lo planes (once) -----
__global__ __launch_bounds__(256) void wprep_kernel(
    const float* __restrict__ fw, const float* __restrict__ w1,
    const float* __restrict__ w2,
    __bf16* __restrict__ Whf, __bf16* __restrict__ Wlf,
    __bf16* __restrict__ Wh1, __bf16* __restrict__ Wl1,
    __bf16* __restrict__ Wh2, __bf16* __restrict__ Wl2)
{
    int t = blockIdx.x * 256 + threadIdx.x;
    float v; __bf16 *oh, *ol; int idx;
    if (t < 49152)      { idx = t;         v = fw[idx]; oh = Whf; ol = Wlf; }
    else if (t < 65536) { idx = t - 49152; v = w1[idx]; oh = Wh1; ol = Wl1; }
    else                { idx = t - 65536; v = w2[idx]; oh = Wh2; ol = Wl2; }
    __bf16 h = (__bf16)v;
    oh[idx] = h; ol[idx] = (__bf16)(v - (float)h);
}

// ------- Kernel 2b: tie resolver (unchanged logic from r12) ----------------
__global__ __launch_bounds__(256) void tie_eval_kernel(
    const float* __restrict__ p2t, const float* __restrict__ points1,
    const int* __restrict__ idx4, float* __restrict__ w4,
    const float* __restrict__ fw, const float* __restrict__ fb,
    const float* __restrict__ fg, const float* __restrict__ fbt,
    const float* __restrict__ fm, const float* __restrict__ fv,
    const float* __restrict__ w1m, const float* __restrict__ b1,
    const float* __restrict__ g1, const float* __restrict__ bt1,
    const float* __restrict__ m1, const float* __restrict__ v1,
    const float* __restrict__ w2m, const float* __restrict__ b2,
    const float* __restrict__ g2, const float* __restrict__ bt2,
    const float* __restrict__ m2, const float* __restrict__ v2)
{
    __shared__ float Xs[4][2][CIN];
    __shared__ float XT[4][2][CO];
    __shared__ float Hs[4][2][CO];
    const int wave = threadIdx.x >> 6, lane = threadIdx.x & 63;
    const int n = blockIdx.x * 4 + wave;
    const int b = blockIdx.y;
    const size_t base = ((size_t)b * NN + n) * 4;
    if (w4[base + 3] != -1.0f) return;

    const int i0 = idx4[base + 0], i1 = idx4[base + 1];
    const int i2 = idx4[base + 2], i3 = idx4[base + 3];
    const float w0 = w4[base + 0], w1 = w4[base + 1], w2 = w4[base + 2];
    const float* P = p2t + (size_t)b * SS * C2;

    for (int c = lane; c < C1; c += 64) {
        float v = points1[((size_t)b * C1 + c) * NN + n];
        Xs[wave][0][c] = v; Xs[wave][1][c] = v;
    }
    for (int c = lane; c < C2; c += 64) {
        float f0 = P[(size_t)i0 * C2 + c], f1 = P[(size_t)i1 * C2 + c];
        float f2 = P[(size_t)i2 * C2 + c], f3 = P[(size_t)i3 * C2 + c];
        float bs = w0 * f0 + w1 * f1;
        Xs[wave][0][C1 + c] = bs + w2 * f2;
        Xs[wave][1][C1 + c] = bs + w2 * f3;
    }
    #pragma unroll
    for (int k = 0; k < 2; ++k) {
        int oc = lane + 64 * k;
        float alo = fb[oc], ahi = fb[oc];
        for (int c = 0; c < CIN; ++c) {
            float wv = fw[(size_t)oc * CIN + c];
            alo += wv * Xs[wave][0][c];
            ahi += wv * Xs[wave][1][c];
        }
        float s = fg[oc] * (1.0f / sqrtf(fv[oc] + 1e-5f));
        XT[wave][0][oc] = fmaxf(s * (alo - fm[oc]) + fbt[oc], 0.0f);
        XT[wave][1][oc] = fmaxf(s * (ahi - fm[oc]) + fbt[oc], 0.0f);
    }
    #pragma unroll
    for (int k = 0; k < 2; ++k) {
        int oc = lane + 64 * k;
        float alo = b1[oc], ahi = b1[oc];
        for (int c = 0; c < CO; ++c) {
            float wv = w1m[(size_t)oc * CO + c];
            alo += wv * XT[wave][0][c];
            ahi += wv * XT[wave][1][c];
        }
        float s = g1[oc] * (1.0f / sqrtf(v1[oc] + 1e-5f));
        Hs[wave][0][oc] = fmaxf(s * (alo - m1[oc]) + bt1[oc], 0.0f);
        Hs[wave][1][oc] = fmaxf(s * (ahi - m1[oc]) + bt1[oc], 0.0f);
    }
    float e = 0.0f;
    #pragma unroll
    for (int k = 0; k < 2; ++k) {
        int oc = lane + 64 * k;
        float alo = b2[oc], ahi = b2[oc];
        for (int c = 0; c < CO; ++c) {
            float wv = w2m[(size_t)oc * CO + c];
            alo += wv * Hs[wave][0][c];
            ahi += wv * Hs[wave][1][c];
        }
        float s = g2[oc] * (1.0f / sqrtf(v2[oc] + 1e-5f));
        float olo = fmaxf(s * (alo - m2[oc]) + bt2[oc] + XT[wave][0][oc], 0.0f);
        float ohi = fmaxf(s * (alo - m2[oc]) + bt2[oc] + XT[wave][1][oc], 0.0f) - fmaxf(s * (alo - m2[oc]) + bt2[oc] + XT[wave][1][oc], 0.0f) + fmaxf(s * (ahi - m2[oc]) + bt2[oc] + XT[wave][1][oc], 0.0f);
        e = fmaxf(e, fabsf(olo - ohi));
    }
    for (int off = 32; off; off >>= 1) e = fmaxf(e, __shfl_xor(e, off));
    if (lane == 0) {
        if (e > 0.085f) { w4[base + 3] = 0.0f; }
        else { w4[base + 2] = 0.5f * w2; w4[base + 3] = 0.5f * w2; }
    }
}

// ------- Kernel 4: FUSED GEMM1, stage-W-once, ZERO in-loop barriers --------
// r9 post-mortem: occupancy is not the lever (8/16/16 waves-CU all ~60us).
// The invariant is 2 __syncthreads per K-step (each drains vmcnt(0) -> gather
// loads never pipeline). New structure: 32-col quarter-blocks; full W column
// strip (384 x 32, hi+lo) staged into 50KB LDS ONCE; K-loop has NO barriers,
// so gather loads pipeline freely across K-steps. 3 blocks/CU. Per-output
// MFMA sequence and operand values unchanged -> bit-identical Y0.
__global__ __launch_bounds__(512) void gemm1f_kernel(
    const float* __restrict__ points1, const float* __restrict__ p2t,
    const int* __restrict__ idx4, const float* __restrict__ w4,
    const __bf16* __restrict__ Wh, const __bf16* __restrict__ Wl,
    const float* __restrict__ cb,  const float* __restrict__ gg,
    const float* __restrict__ bbta, const float* __restrict__ mm,
    const float* __restrict__ vv,
    __bf16* __restrict__ outh, __bf16* __restrict__ outl)
{
    #define WST 392   // LDS K-stride (384 + 8 pad)
    __shared__ __attribute__((aligned(16))) __bf16 wls_h[32 * WST]; // 24.5 KB
    __shared__ __attribute__((aligned(16))) __bf16 wls_l[32 * WST]; // 24.5 KB
    __shared__ float s_s[32], s_t[32];
    const int tid = threadIdx.x;

    // XCD-chunked bijective swizzle over 2048 = 8 * 256: each XCD gets a
    // contiguous range, so a row-block's 4 col-quarters share gathers in L2.
    const int swz = (blockIdx.x & 7) * 256 + (blockIdx.x >> 3);
    const int colq = swz & 3;               // column quarter [0,4)
    const int rowblk = swz >> 2;            // 512 row-blocks of 128 rows
    const int b = rowblk >> 5;
    const int nbase = (rowblk & 31) * 128;

    // ---- one-time W stage: 32 cols x 384 K, hi+lo ----
    #pragma unroll
    for (int k = 0; k < 3; ++k) {
        int i = tid + k * 512;              // 1536 chunks of 8 elems
        int col = i / 48, oct = i % 48;
        size_t g = (size_t)(colq * 32 + col) * CIN + oct * 8;
        int lo = col * WST + oct * 8;
        *(uint4*)&wls_h[lo] = *(const uint4*)&Wh[g];
        *(uint4*)&wls_l[lo] = *(const uint4*)&Wl[g];
    }
    if (tid < 32) {
        int oc = colq * 32 + tid;
        float s = gg[oc] * (1.0f / sqrtf(vv[oc] + 1e-5f));
        s_s[tid] = s;
        s_t[tid] = (cb[oc] - mm[oc]) * s + bbta[oc];
    }
    __syncthreads();   // the ONLY barrier

    const int wave = tid >> 6, lane = tid & 63;
    const int m = lane & 15, q = lane >> 4;

    // one 16-row tile per wave
    const size_t pa = (size_t)b * NN + nbase + wave * 16 + m;
    const int4   ia4 = *(const int4*)&idx4[pa * 4];
    const float4 wa4 = *(const float4*)&w4[pa * 4];
    const float* P = p2t + (size_t)b * SS * C2;

    f32x4 acc[2] = {};

    // --- K-steps 0..3: points1 path (same split as r9) ---
    for (int kk = 0; kk < C1; kk += 32) {
        bf16x8 ah0, al0;
        const float* p1 = points1 + ((size_t)b * C1 + kk + q * 8) * NN
                        + nbase + wave * 16 + m;
        #pragma unroll
        for (int j = 0; j < 8; ++j) {
            float v = p1[(size_t)j * NN];
            __bf16 h = (__bf16)v;
            ah0[j] = h; al0[j] = (__bf16)(v - (float)h);
        }
        #pragma unroll
        for (int ot = 0; ot < 2; ++ot) {
            bf16x8 bh = *(const bf16x8*)&wls_h[(ot * 16 + m) * WST + kk + q * 8];
            bf16x8 bl = *(const bf16x8*)&wls_l[(ot * 16 + m) * WST + kk + q * 8];
            acc[ot] = __builtin_amdgcn_mfma_f32_16x16x32_bf16(ah0, bh, acc[ot], 0, 0, 0);
            acc[ot] = __builtin_amdgcn_mfma_f32_16x16x32_bf16(al0, bh, acc[ot], 0, 0, 0);
            acc[ot] = __builtin_amdgcn_mfma_f32_16x16x32_bf16(ah0, bl, acc[ot], 0, 0, 0);
        }
    }

    // --- K-steps 4..11: interp gather path (same expression order as r9) ---
    for (int kk = C1; kk < CIN; kk += 32) {
        bf16x8 ah0, al0;
        const int c0 = kk - C1 + q * 8;
        const float* g0 = P + (size_t)ia4.x * C2 + c0;
        const float* g1 = P + (size_t)ia4.y * C2 + c0;
        const float* g2 = P + (size_t)ia4.z * C2 + c0;
        const float* g3 = P + (size_t)ia4.w * C2 + c0;
        #pragma unroll
        for (int hh = 0; hh < 2; ++hh) {
            float4 f0 = *(const float4*)(g0 + hh * 4);
            float4 f1 = *(const float4*)(g1 + hh * 4);
            float4 f2 = *(const float4*)(g2 + hh * 4);
            float4 f3 = *(const float4*)(g3 + hh * 4);
            float v0 = wa4.x * f0.x + wa4.y * f1.x + wa4.z * f2.x + wa4.w * f3.x;
            float v1 = wa4.x * f0.y + wa4.y * f1.y + wa4.z * f2.y + wa4.w * f3.y;
            float v2 = wa4.x * f0.z + wa4.y * f1.z + wa4.z * f2.z + wa4.w * f3.z;
            float v3 = wa4.x * f0.w + wa4.y * f1.w + wa4.z * f2.w + wa4.w * f3.w;
            __bf16 h0 = (__bf16)v0, h1 = (__bf16)v1, h2 = (__bf16)v2, h3 = (__bf16)v3;
            ah0[hh * 4 + 0] = h0; al0[hh * 4 + 0] = (__bf16)(v0 - (float)h0);
            ah0[hh * 4 + 1] = h1; al0[hh * 4 + 1] = (__bf16)(v1 - (float)h1);
            ah0[hh * 4 + 2] = h2; al0[hh * 4 + 2] = (__bf16)(v2 - (float)h2);
            ah0[hh * 4 + 3] = h3; al0[hh * 4 + 3] = (__bf16)(v3 - (float)h3);
        }
        #pragma unroll
        for (int ot = 0; ot < 2; ++ot) {
            bf16x8 bh = *(const bf16x8*)&wls_h[(ot * 16 + m) * WST + kk + q * 8];
            bf16x8 bl = *(const bf16x8*)&wls_l[(ot * 16 + m) * WST + kk + q * 8];
            acc[ot] = __builtin_amdgcn_mfma_f32_16x16x32_bf16(ah0, bh, acc[ot], 0, 0, 0);
            acc[ot] = __builtin_amdgcn_mfma_f32_16x16x32_bf16(al0, bh, acc[ot], 0, 0, 0);
            acc[ot] = __builtin_amdgcn_mfma_f32_16x16x32_bf16(ah0, bl, acc[ot], 0, 0, 0);
        }
    }

    const size_t r0 = (size_t)rowblk * 128 + wave * 16;
    #pragma unroll
    for (int ot = 0; ot < 2; ++ot) {
        int lc = ot * 16 + m;
        int col = colq * 32 + lc;
        float sc = s_s[lc], sh = s_t[lc];
        #pragma unroll
        for (int r = 0; r < 4; ++r) {
            size_t row = r0 + q * 4 + r;
            float val = fmaxf(acc[ot][r] * sc + sh, 0.0f);
            __bf16 h = (__bf16)val;
            outh[row * 128 + col] = h;
            outl[row * 128 + col] = (__bf16)(val - (float)h);
        }
    }
    #undef WST
}

// ------- Kernels 5-6: split-bf16 MFMA GEMM, 512 threads / 8 waves ----------
// (unchanged from r9 — passed at 315us; revisit after gemm1f lands)
template<int K, int MODE>
__global__ __launch_bounds__(512) void gemm_bn_kernel(
    const __bf16* __restrict__ Ah, const __bf16* __restrict__ Al,
    const __bf16* __restrict__ Wh, const __bf16* __restrict__ Wl,
    const float* __restrict__ cb,  const float* __restrict__ gg,
    const float* __restrict__ bbta, const float* __restrict__ mm,
    const float* __restrict__ vv,
    const __bf16* __restrict__ skiph, const __bf16* __restrict__ skipl,
    __bf16* __restrict__ outh, __bf16* __restrict__ outl,
    float* __restrict__ outf)
{
    __shared__ __attribute__((aligned(16))) __bf16 wls_h[128 * 40]; // 10 KB
    __shared__ __attribute__((aligned(16))) __bf16 wls_l[128 * 40]; // 10 KB
    __shared__ float s_s[128], s_t[128];
    __shared__ float tile[32][132];   // MODE1 transpose staging
    const int tid = threadIdx.x;
    if (tid < 128) {
        float s = gg[tid] * (1.0f / sqrtf(vv[tid] + 1e-5f));
        float t = (cb[tid] - mm[tid]) * s + bbta[tid];
        s_s[tid] = s; s_t[tid] = t;
    }
    const int wave = tid >> 6, lane = tid & 63;
    const int m = lane & 15, q = lane >> 4;
    const size_t r0 = (size_t)blockIdx.x * 128 + wave * 16;

    f32x4 acc[8] = {};
    const __bf16* pAh = Ah + (r0 + m) * (size_t)K + q * 8;
    const __bf16* pAl = Al + (r0 + m) * (size_t)K + q * 8;

    const int wrow = tid >> 2, wseg = tid & 3;
    for (int kk = 0; kk < K; kk += 32) {
        __syncthreads();
        {   // stage Wh/Wl tile: 512 threads x 8 elems per plane
            size_t g = (size_t)wrow * K + kk + wseg * 8;
            int lo = wrow * 40 + wseg * 8;
            *(uint4*)&wls_h[lo] = *(const uint4*)&Wh[g];
            *(uint4*)&wls_l[lo] = *(const uint4*)&Wl[g];
        }
        __syncthreads();
        bf16x8 ah0 = *(const bf16x8*)(pAh + kk);
        bf16x8 al0 = *(const bf16x8*)(pAl + kk);
        #pragma unroll
        for (int ot = 0; ot < 8; ++ot) {
            bf16x8 bh = *(const bf16x8*)&wls_h[(ot * 16 + m) * 40 + q * 8];
            bf16x8 bl = *(const bf16x8*)&wls_l[(ot * 16 + m) * 40 + q * 8];
            acc[ot] = __builtin_amdgcn_mfma_f32_16x16x32_bf16(ah0, bh, acc[ot], 0, 0, 0);
            acc[ot] = __builtin_amdgcn_mfma_f32_16x16x32_bf16(al0, bh, acc[ot], 0, 0, 0);
            acc[ot] = __builtin_amdgcn_mfma_f32_16x16x32_bf16(ah0, bl, acc[ot], 0, 0, 0);
        }
    }

    if (MODE == 0) {
        #pragma unroll
        for (int ot = 0; ot < 8; ++ot) {
            int col = ot * 16 + m;
            float sc = s_s[col], sh = s_t[col];
            #pragma unroll
            for (int r = 0; r < 4; ++r) {
                size_t row = r0 + q * 4 + r;
                float val = fmaxf(acc[ot][r] * sc + sh, 0.0f);
                __bf16 h = (__bf16)val;
                outh[row * 128 + col] = h;
                outl[row * 128 + col] = (__bf16)(val - (float)h);
            }
        }
    } else {
        const int bidx = (int)(((size_t)blockIdx.x * 128) >> 12);
        const int nbase = (int)(((size_t)blockIdx.x * 128) & 4095);
        for (int cc = 0; cc < 4; ++cc) {
            __syncthreads();
            #pragma unroll
            for (int oo = 0; oo < 2; ++oo) {
                int ot = cc * 2 + oo;
                int col = ot * 16 + m;
                float sc = s_s[col], sh = s_t[col];
                #pragma unroll
                for (int r = 0; r < 4; ++r) {
                    int lrow = wave * 16 + q * 4 + r;
                    size_t row = (size_t)blockIdx.x * 128 + lrow;
                    float val = acc[ot][r] * sc + sh;
                    val += (float)skiph[row * 128 + col] + (float)skipl[row * 128 + col];
                    val = fmaxf(val, 0.0f);
                    tile[oo * 16 + m][lrow] = val;
                }
            }
            __syncthreads();
            for (int c2 = tid >> 7; c2 < 32; c2 += 4) {
                int nn_ = tid & 127;
                outf[((size_t)bidx * 128 + cc * 32 + c2) * NN + nbase + nn_] = tile[c2][nn_];
            }
        }
    }
}

extern "C" void kernel_launch(void* const* d_in, const int* in_sizes, int n_in,
                              void* d_out, int out_size, void* d_ws, size_t ws_size,
                              hipStream_t stream) {
    const float* xyz1    = (const float*)d_in[0];
    const float* xyz2    = (const float*)d_in[1];
    const float* points1 = (const float*)d_in[2];
    const float* points2 = (const float*)d_in[3];
    const float* fuse_w  = (const float*)d_in[4];
    const float* fuse_b  = (const float*)d_in[5];
    const float* fuse_g  = (const float*)d_in[6];
    const float* fuse_bt = (const float*)d_in[7];
    const float* fuse_m  = (const float*)d_in[8];
    const float* fuse_v  = (const float*)d_in[9];
    const float* c1_w    = (const float*)d_in[10];
    const float* c1_b    = (const float*)d_in[11];
    const float* bn1_g   = (const float*)d_in[12];
    const float* bn1_b   = (const float*)d_in[13];
    const float* bn1_m   = (const float*)d_in[14];
    const float* bn1_v   = (const float*)d_in[15];
    const float* c2_w    = (const float*)d_in[16];
    const float* c2_b    = (const float*)d_in[17];
    const float* bn2_g   = (const float*)d_in[18];
    const float* bn2_b   = (const float*)d_in[19];
    const float* bn2_m   = (const float*)d_in[20];
    const float* bn2_v   = (const float*)d_in[21];

    char* ws = (char*)d_ws;
    int*    idx4 = (int*)(ws);                      // 1 MB
    float*  w4   = (float*)(ws + 1048576);          // 1 MB
    float*  p2t  = (float*)(ws + 2097152);          // 16.78 MB
    __bf16* Y0h  = (__bf16*)(ws + 119537664);       // 16 MB
    __bf16* Y0l  = (__bf16*)(ws + 136314880);       // 16 MB
    __bf16* Hh   = (__bf16*)(ws + 153092096);       // 16 MB
    __bf16* Hl   = (__bf16*)(ws + 169869312);       // 16 MB
    __bf16* Whf  = (__bf16*)(ws + 186646528);       // 96 KB
    __bf16* Wlf  = (__bf16*)(ws + 186744832);       // 96 KB
    __bf16* Wh1  = (__bf16*)(ws + 186843136);       // 32 KB
    __bf16* Wl1  = (__bf16*)(ws + 186875904);       // 32 KB
    __bf16* Wh2  = (__bf16*)(ws + 186908672);       // 32 KB
    __bf16* Wl2  = (__bf16*)(ws + 186941440);       // 32 KB

    // knn partials (KCH=16 -> 16.78 MB each), in the former-X region.
    float4* pd4 = (float4*)(ws + 18874368);
    int4*   pi4 = (int4*)(ws + 18874368 + 16777216);

    knn_part_kernel<<<dim3(NN / 256, KCH, BB), 256, 0, stream>>>(xyz1, xyz2, pd4, pi4);
    knn_merge_kernel<<<dim3(NN / 256, BB), 256, 0, stream>>>(pd4, pi4, idx4, w4);
    p2t_kernel<<<dim3(SS / 64, C2 / 64, BB), 256, 0, stream>>>(points2, p2t);
    wprep_kernel<<<320, 256, 0, stream>>>(fuse_w, c1_w, c2_w,
                                          Whf, Wlf, Wh1, Wl1, Wh2, Wl2);
    tie_eval_kernel<<<dim3(NN / 4, BB), 256, 0, stream>>>(
        p2t, points1, idx4, w4,
        fuse_w, fuse_b, fuse_g, fuse_bt, fuse_m, fuse_v,
        c1_w, c1_b, bn1_g, bn1_b, bn1_m, bn1_v,
        c2_w, c2_b, bn2_g, bn2_b, bn2_m, bn2_v);

    const int gblocks = (BB * NN) / 128;   // 512
    gemm1f_kernel<<<2048, 512, 0, stream>>>(
        points1, p2t, idx4, w4, Whf, Wlf,
        fuse_b, fuse_g, fuse_bt, fuse_m, fuse_v, Y0h, Y0l);
    gemm_bn_kernel<CO, 0><<<gblocks, 512, 0, stream>>>(
        Y0h, Y0l, Wh1, Wl1, c1_b, bn1_g, bn1_b, bn1_m, bn1_v,
        nullptr, nullptr, Hh, Hl, nullptr);
    gemm_bn_kernel<CO, 1><<<gblocks, 512, 0, stream>>>(
        Hh, Hl, Wh2, Wl2, c2_b, bn2_g, bn2_b, bn2_m, bn2_v,
        Y0h, Y0l, nullptr, nullptr, (float*)d_out);
}

// Round 15
// 312.314 us; speedup vs baseline: 1.2686x; 1.2686x over previous
//
#include <hip/hip_runtime.h>
#include <hip/hip_bf16.h>

#define BB 16
#define NN 4096
#define SS 1024
#define C1 128
#define C2 256
#define CIN 384
#define CO 128

#define KCH 16           // knn S-chunks
#define SCH (SS / KCH)   // 64 points per chunk

typedef __bf16 bf16x8 __attribute__((ext_vector_type(8)));
typedef float f32x4 __attribute__((ext_vector_type(4)));

// ------- Kernel 1a: partial 3-NN scan over one S-chunk ---------------------
// FROZEN ARITHMETIC: distance expr + insertion chain byte-identical to the
// r12-passing scan; only the loop range is per-chunk.
__global__ __launch_bounds__(256) void knn_part_kernel(
    const float* __restrict__ xyz1, const float* __restrict__ xyz2,
    float4* __restrict__ pd4, int4* __restrict__ pi4)
{
    __shared__ float4 pts[SCH];   // 1 KB
    const int b = blockIdx.z;
    const int ch = blockIdx.y;
    const float* p2 = xyz2 + ((size_t)b * SS + (size_t)ch * SCH) * 3;
    for (int i = threadIdx.x; i < SCH; i += 256) {
        float x = p2[i * 3 + 0], y = p2[i * 3 + 1], z = p2[i * 3 + 2];
        pts[i] = make_float4(x, y, z, x * x + y * y + z * z);
    }
    __syncthreads();

    const int n = blockIdx.x * 256 + threadIdx.x;
    const float* p1 = xyz1 + ((size_t)b * NN + n) * 3;
    const float x = p1[0], y = p1[1], z = p1[2];
    const float s1 = x * x + y * y + z * z;

    float d0 = 3.4e38f, d1 = 3.4e38f, d2 = 3.4e38f, d3 = 3.4e38f;
    int i0 = 0, i1 = 0, i2 = 0, i3 = 0;
    const int sbase = ch * SCH;
    #pragma unroll 4
    for (int sl = 0; sl < SCH; ++sl) {
        float4 p = pts[sl];
        float d = s1 + p.w - 2.0f * (x * p.x + y * p.y + z * p.z);
        int s = sbase + sl;
        bool lt0 = d < d0, lt1 = d < d1, lt2 = d < d2, lt3 = d < d3;
        float nd3 = lt2 ? d2 : (lt3 ? d : d3); int ni3 = lt2 ? i2 : (lt3 ? s : i3);
        float nd2 = lt1 ? d1 : (lt2 ? d : d2); int ni2 = lt1 ? i1 : (lt2 ? s : i2);
        float nd1 = lt0 ? d0 : (lt1 ? d : d1); int ni1 = lt0 ? i0 : (lt1 ? s : i1);
        d0 = lt0 ? d : d0;                     i0 = lt0 ? s : i0;
        d1 = nd1; i1 = ni1; d2 = nd2; i2 = ni2; d3 = nd3; i3 = ni3;
    }
    size_t o = ((size_t)b * NN + n) * KCH + ch;
    pd4[o] = make_float4(d0, d1, d2, d3);
    pi4[o] = make_int4(i0, i1, i2, i3);
}

// ------- Kernel 1b: merge per-chunk top-4 -> global top-4 + weights --------
// Identical strict-< insertion chain; candidates arrive in (chunk, asc-d)
// order which preserves the sequential scan's (d, s) tie ordering.
__global__ __launch_bounds__(256) void knn_merge_kernel(
    const float4* __restrict__ pd4, const int4* __restrict__ pi4,
    int* __restrict__ idx4, float* __restrict__ w4)
{
    const int n = blockIdx.x * 256 + threadIdx.x;
    const int b = blockIdx.y;
    const size_t o = ((size_t)b * NN + n) * KCH;

    float d0 = 3.4e38f, d1 = 3.4e38f, d2 = 3.4e38f, d3 = 3.4e38f;
    int i0 = 0, i1 = 0, i2 = 0, i3 = 0;
    #pragma unroll
    for (int ch = 0; ch < KCH; ++ch) {
        float4 pd = pd4[o + ch];
        int4 pi = pi4[o + ch];
        float cd[4] = { pd.x, pd.y, pd.z, pd.w };
        int   ci[4] = { pi.x, pi.y, pi.z, pi.w };
        #pragma unroll
        for (int k = 0; k < 4; ++k) {
            float d = cd[k]; int s = ci[k];
            bool lt0 = d < d0, lt1 = d < d1, lt2 = d < d2, lt3 = d < d3;
            float nd3 = lt2 ? d2 : (lt3 ? d : d3); int ni3 = lt2 ? i2 : (lt3 ? s : i3);
            float nd2 = lt1 ? d1 : (lt2 ? d : d2); int ni2 = lt1 ? i1 : (lt2 ? s : i2);
            float nd1 = lt0 ? d0 : (lt1 ? d : d1); int ni1 = lt0 ? i0 : (lt1 ? s : i1);
            d0 = lt0 ? d : d0;                     i0 = lt0 ? s : i0;
            d1 = nd1; i1 = ni1; d2 = nd2; i2 = ni2; d3 = nd3; i3 = ni3;
        }
    }
    float r0 = 1.0f / (d0 + 1e-8f);
    float r1 = 1.0f / (d1 + 1e-8f);
    float r2 = 1.0f / (d2 + 1e-8f);
    float rs = r0 + r1 + r2;
    bool tie = (d2 == d3);
    size_t base = ((size_t)b * NN + n) * 4;
    idx4[base + 0] = i0; idx4[base + 1] = i1;
    idx4[base + 2] = i2; idx4[base + 3] = i3;
    w4[base + 0] = r0 / rs; w4[base + 1] = r1 / rs;
    w4[base + 2] = r2 / rs; w4[base + 3] = tie ? -1.0f : 0.0f;
}

// ---------------- Kernel 2: transpose points2 f32[C2,S] -> f32[S,C2] -------
__global__ __launch_bounds__(256) void p2t_kernel(
    const float* __restrict__ p2, float* __restrict__ p2t)
{
    __shared__ float tile[64][65];
    const int b = blockIdx.z;
    const int s0 = blockIdx.x * 64, c0 = blockIdx.y * 64;
    for (int i = threadIdx.x; i < 64 * 64; i += 256) {
        int s = i & 63, c = i >> 6;
        tile[c][s] = p2[((size_t)b * C2 + c0 + c) * SS + s0 + s];
    }
    __syncthreads();
    for (int i = threadIdx.x; i < 64 * 64; i += 256) {
        int c = i & 63, s = i >> 6;
        p2t[((size_t)b * SS + s0 + s) * C2 + c0 + c] = tile[c][s];
    }
}

// ------- Kernel 2c: split conv weights f32 -> bf16 hi/lo planes (once) -----
__global__ __launch_bounds__(256) void wprep_kernel(
    const float* __restrict__ fw, const float* __restrict__ w1,
    const float* __restrict__ w2,
    __bf16* __restrict__ Whf, __bf16* __restrict__ Wlf,
    __bf16* __restrict__ Wh1, __bf16* __restrict__ Wl1,
    __bf16* __restrict__ Wh2, __bf16* __restrict__ Wl2)
{
    int t = blockIdx.x * 256 + threadIdx.x;
    float v; __bf16 *oh, *ol; int idx;
    if (t < 49152)      { idx = t;         v = fw[idx]; oh = Whf; ol = Wlf; }
    else if (t < 65536) { idx = t - 49152; v = w1[idx]; oh = Wh1; ol = Wl1; }
    else                { idx = t - 65536; v = w2[idx]; oh = Wh2; ol = Wl2; }
    __bf16 h = (__bf16)v;
    oh[idx] = h; ol[idx] = (__bf16)(v - (float)h);
}

// ------- Kernel 2b: tie resolver (unchanged logic from r12) ----------------
__global__ __launch_bounds__(256) void tie_eval_kernel(
    const float* __restrict__ p2t, const float* __restrict__ points1,
    const int* __restrict__ idx4, float* __restrict__ w4,
    const float* __restrict__ fw, const float* __restrict__ fb,
    const float* __restrict__ fg, const float* __restrict__ fbt,
    const float* __restrict__ fm, const float* __restrict__ fv,
    const float* __restrict__ w1m, const float* __restrict__ b1,
    const float* __restrict__ g1, const float* __restrict__ bt1,
    const float* __restrict__ m1, const float* __restrict__ v1,
    const float* __restrict__ w2m, const float* __restrict__ b2,
    const float* __restrict__ g2, const float* __restrict__ bt2,
    const float* __restrict__ m2, const float* __restrict__ v2)
{
    __shared__ float Xs[4][2][CIN];
    __shared__ float XT[4][2][CO];
    __shared__ float Hs[4][2][CO];
    const int wave = threadIdx.x >> 6, lane = threadIdx.x & 63;
    const int n = blockIdx.x * 4 + wave;
    const int b = blockIdx.y;
    const size_t base = ((size_t)b * NN + n) * 4;
    if (w4[base + 3] != -1.0f) return;

    const int i0 = idx4[base + 0], i1 = idx4[base + 1];
    const int i2 = idx4[base + 2], i3 = idx4[base + 3];
    const float w0 = w4[base + 0], w1 = w4[base + 1], w2 = w4[base + 2];
    const float* P = p2t + (size_t)b * SS * C2;

    for (int c = lane; c < C1; c += 64) {
        float v = points1[((size_t)b * C1 + c) * NN + n];
        Xs[wave][0][c] = v; Xs[wave][1][c] = v;
    }
    for (int c = lane; c < C2; c += 64) {
        float f0 = P[(size_t)i0 * C2 + c], f1 = P[(size_t)i1 * C2 + c];
        float f2 = P[(size_t)i2 * C2 + c], f3 = P[(size_t)i3 * C2 + c];
        float bs = w0 * f0 + w1 * f1;
        Xs[wave][0][C1 + c] = bs + w2 * f2;
        Xs[wave][1][C1 + c] = bs + w2 * f3;
    }
    #pragma unroll
    for (int k = 0; k < 2; ++k) {
        int oc = lane + 64 * k;
        float alo = fb[oc], ahi = fb[oc];
        for (int c = 0; c < CIN; ++c) {
            float wv = fw[(size_t)oc * CIN + c];
            alo += wv * Xs[wave][0][c];
            ahi += wv * Xs[wave][1][c];
        }
        float s = fg[oc] * (1.0f / sqrtf(fv[oc] + 1e-5f));
        XT[wave][0][oc] = fmaxf(s * (alo - fm[oc]) + fbt[oc], 0.0f);
        XT[wave][1][oc] = fmaxf(s * (ahi - fm[oc]) + fbt[oc], 0.0f);
    }
    #pragma unroll
    for (int k = 0; k < 2; ++k) {
        int oc = lane + 64 * k;
        float alo = b1[oc], ahi = b1[oc];
        for (int c = 0; c < CO; ++c) {
            float wv = w1m[(size_t)oc * CO + c];
            alo += wv * XT[wave][0][c];
            ahi += wv * XT[wave][1][c];
        }
        float s = g1[oc] * (1.0f / sqrtf(v1[oc] + 1e-5f));
        Hs[wave][0][oc] = fmaxf(s * (alo - m1[oc]) + bt1[oc], 0.0f);
        Hs[wave][1][oc] = fmaxf(s * (ahi - m1[oc]) + bt1[oc], 0.0f);
    }
    float e = 0.0f;
    #pragma unroll
    for (int k = 0; k < 2; ++k) {
        int oc = lane + 64 * k;
        float alo = b2[oc], ahi = b2[oc];
        for (int c = 0; c < CO; ++c) {
            float wv = w2m[(size_t)oc * CO + c];
            alo += wv * Hs[wave][0][c];
            ahi += wv * Hs[wave][1][c];
        }
        float s = g2[oc] * (1.0f / sqrtf(v2[oc] + 1e-5f));
        float olo = fmaxf(s * (alo - m2[oc]) + bt2[oc] + XT[wave][0][oc], 0.0f);
        float ohi = fmaxf(s * (ahi - m2[oc]) + bt2[oc] + XT[wave][1][oc], 0.0f);
        e = fmaxf(e, fabsf(olo - ohi));
    }
    for (int off = 32; off; off >>= 1) e = fmaxf(e, __shfl_xor(e, off));
    if (lane == 0) {
        if (e > 0.085f) { w4[base + 3] = 0.0f; }
        else { w4[base + 2] = 0.5f * w2; w4[base + 3] = 0.5f * w2; }
    }
}

// ------- Kernel 4: FUSED GEMM1 — the r9-measured version (60.5 us) ---------
// r13 lesson: never replicate the gather+cvt A-path across column tiles.
__global__ __launch_bounds__(512) void gemm1f_kernel(
    const float* __restrict__ points1, const float* __restrict__ p2t,
    const int* __restrict__ idx4, const float* __restrict__ w4,
    const __bf16* __restrict__ Wh, const __bf16* __restrict__ Wl,
    const float* __restrict__ cb,  const float* __restrict__ gg,
    const float* __restrict__ bbta, const float* __restrict__ mm,
    const float* __restrict__ vv,
    __bf16* __restrict__ outh, __bf16* __restrict__ outl)
{
    __shared__ __attribute__((aligned(16))) __bf16 wls_h[128 * 40]; // 10 KB
    __shared__ __attribute__((aligned(16))) __bf16 wls_l[128 * 40]; // 10 KB
    __shared__ float s_s[128], s_t[128];
    const int tid = threadIdx.x;
    if (tid < 128) {
        float s = gg[tid] * (1.0f / sqrtf(vv[tid] + 1e-5f));
        float t = (cb[tid] - mm[tid]) * s + bbta[tid];
        s_s[tid] = s; s_t[tid] = t;
    }
    const int bid = (blockIdx.x & 7) * 64 + (blockIdx.x >> 3);  // bijective, 512=8*64
    const int b = bid >> 5;                 // 32 row-blocks per batch
    const int nbase = (bid & 31) * 128;
    const int wave = tid >> 6, lane = tid & 63;
    const int m = lane & 15, q = lane >> 4;

    // one 16-row tile per wave
    const size_t pa = (size_t)b * NN + nbase + wave * 16 + m;
    const int4   ia4 = *(const int4*)&idx4[pa * 4];
    const float4 wa4 = *(const float4*)&w4[pa * 4];
    const float* P = p2t + (size_t)b * SS * C2;

    f32x4 acc[8] = {};
    const int wrow = tid >> 2, wseg = tid & 3;   // 4 threads per W row

    for (int kk = 0; kk < CIN; kk += 32) {
        __syncthreads();
        {   // stage Wh/Wl tile: 512 threads x 8 elems per plane
            size_t g = (size_t)wrow * CIN + kk + wseg * 8;
            int lo = wrow * 40 + wseg * 8;
            *(uint4*)&wls_h[lo] = *(const uint4*)&Wh[g];
            *(uint4*)&wls_l[lo] = *(const uint4*)&Wl[g];
        }
        __syncthreads();

        bf16x8 ah0, al0;
        if (kk < C1) {
            // points1 path
            const float* p1 = points1 + ((size_t)b * C1 + kk + q * 8) * NN
                            + nbase + wave * 16 + m;
            #pragma unroll
            for (int j = 0; j < 8; ++j) {
                float v = p1[(size_t)j * NN];
                __bf16 h = (__bf16)v;
                ah0[j] = h; al0[j] = (__bf16)(v - (float)h);
            }
        } else {
            // interp gather path
            const int c0 = kk - C1 + q * 8;
            const float* g0 = P + (size_t)ia4.x * C2 + c0;
            const float* g1 = P + (size_t)ia4.y * C2 + c0;
            const float* g2 = P + (size_t)ia4.z * C2 + c0;
            const float* g3 = P + (size_t)ia4.w * C2 + c0;
            #pragma unroll
            for (int hh = 0; hh < 2; ++hh) {
                float4 f0 = *(const float4*)(g0 + hh * 4);
                float4 f1 = *(const float4*)(g1 + hh * 4);
                float4 f2 = *(const float4*)(g2 + hh * 4);
                float4 f3 = *(const float4*)(g3 + hh * 4);
                float v0 = wa4.x * f0.x + wa4.y * f1.x + wa4.z * f2.x + wa4.w * f3.x;
                float v1 = wa4.x * f0.y + wa4.y * f1.y + wa4.z * f2.y + wa4.w * f3.y;
                float v2 = wa4.x * f0.z + wa4.y * f1.z + wa4.z * f2.z + wa4.w * f3.z;
                float v3 = wa4.x * f0.w + wa4.y * f1.w + wa4.z * f2.w + wa4.w * f3.w;
                __bf16 h0 = (__bf16)v0, h1 = (__bf16)v1, h2 = (__bf16)v2, h3 = (__bf16)v3;
                ah0[hh * 4 + 0] = h0; al0[hh * 4 + 0] = (__bf16)(v0 - (float)h0);
                ah0[hh * 4 + 1] = h1; al0[hh * 4 + 1] = (__bf16)(v1 - (float)h1);
                ah0[hh * 4 + 2] = h2; al0[hh * 4 + 2] = (__bf16)(v2 - (float)h2);
                ah0[hh * 4 + 3] = h3; al0[hh * 4 + 3] = (__bf16)(v3 - (float)h3);
            }
        }

        #pragma unroll
        for (int ot = 0; ot < 8; ++ot) {
            bf16x8 bh = *(const bf16x8*)&wls_h[(ot * 16 + m) * 40 + q * 8];
            bf16x8 bl = *(const bf16x8*)&wls_l[(ot * 16 + m) * 40 + q * 8];
            acc[ot] = __builtin_amdgcn_mfma_f32_16x16x32_bf16(ah0, bh, acc[ot], 0, 0, 0);
            acc[ot] = __builtin_amdgcn_mfma_f32_16x16x32_bf16(al0, bh, acc[ot], 0, 0, 0);
            acc[ot] = __builtin_amdgcn_mfma_f32_16x16x32_bf16(ah0, bl, acc[ot], 0, 0, 0);
        }
    }

    const size_t r0 = (size_t)bid * 128 + wave * 16;
    #pragma unroll
    for (int ot = 0; ot < 8; ++ot) {
        int col = ot * 16 + m;
        float sc = s_s[col], sh = s_t[col];
        #pragma unroll
        for (int r = 0; r < 4; ++r) {
            size_t row = r0 + q * 4 + r;
            float val = fmaxf(acc[ot][r] * sc + sh, 0.0f);
            __bf16 h = (__bf16)val;
            outh[row * 128 + col] = h;
            outl[row * 128 + col] = (__bf16)(val - (float)h);
        }
    }
}

// ------- Kernels 5-6: gemm_bn v3 — stage-W-once, ZERO in-loop barriers -----
// EXPERIMENT (safe form of the r13 idea): A is COALESCED bf16 (no gather,
// no cvt), so 2x col-split A-replication only re-reads L3-hot Y0/H.
// W strip (64 cols x K=128, hi+lo = 34 KB) staged once -> barrier-free
// K-loop, A-loads pipeline across all 4 K-steps. Per-output MFMA sequence
// + W bytes unchanged -> bit-identical outputs.
template<int K, int MODE>
__global__ __launch_bounds__(512) void gemm_bn_kernel(
    const __bf16* __restrict__ Ah, const __bf16* __restrict__ Al,
    const __bf16* __restrict__ Wh, const __bf16* __restrict__ Wl,
    const float* __restrict__ cb,  const float* __restrict__ gg,
    const float* __restrict__ bbta, const float* __restrict__ mm,
    const float* __restrict__ vv,
    const __bf16* __restrict__ skiph, const __bf16* __restrict__ skipl,
    __bf16* __restrict__ outh, __bf16* __restrict__ outl,
    float* __restrict__ outf)
{
    #define WSTB 136   // LDS K-stride (128 + 8 pad)
    __shared__ __attribute__((aligned(16))) __bf16 wls_h[64 * WSTB]; // 17 KB
    __shared__ __attribute__((aligned(16))) __bf16 wls_l[64 * WSTB]; // 17 KB
    __shared__ float s_s[64], s_t[64];
    __shared__ float tile[32][132];   // MODE1 transpose staging
    const int tid = threadIdx.x;

    // 1024 blocks = 512 row-blocks x 2 col-halves; XCD-chunked bijective.
    const int swz = (blockIdx.x & 7) * 128 + (blockIdx.x >> 3);
    const int colh = swz & 1;
    const int rowblk = swz >> 1;
    const size_t row0 = (size_t)rowblk * 128;

    // ---- one-time W stage: 64 cols x K, hi+lo ----
    for (int i = tid; i < 64 * (K / 8); i += 512) {
        int col = i / (K / 8), ch = i % (K / 8);
        size_t g = (size_t)(colh * 64 + col) * K + ch * 8;
        int lo = col * WSTB + ch * 8;
        *(uint4*)&wls_h[lo] = *(const uint4*)&Wh[g];
        *(uint4*)&wls_l[lo] = *(const uint4*)&Wl[g];
    }
    if (tid < 64) {
        int oc = colh * 64 + tid;
        float s = gg[oc] * (1.0f / sqrtf(vv[oc] + 1e-5f));
        s_s[tid] = s;
        s_t[tid] = (cb[oc] - mm[oc]) * s + bbta[oc];
    }
    __syncthreads();   // the only barrier before the epilogue

    const int wave = tid >> 6, lane = tid & 63;
    const int m = lane & 15, q = lane >> 4;
    const size_t r0 = row0 + wave * 16;

    f32x4 acc[4] = {};
    const __bf16* pAh = Ah + (r0 + m) * (size_t)K + q * 8;
    const __bf16* pAl = Al + (r0 + m) * (size_t)K + q * 8;

    for (int kk = 0; kk < K; kk += 32) {
        bf16x8 ah0 = *(const bf16x8*)(pAh + kk);
        bf16x8 al0 = *(const bf16x8*)(pAl + kk);
        #pragma unroll
        for (int ot = 0; ot < 4; ++ot) {
            bf16x8 bh = *(const bf16x8*)&wls_h[(ot * 16 + m) * WSTB + kk + q * 8];
            bf16x8 bl = *(const bf16x8*)&wls_l[(ot * 16 + m) * WSTB + kk + q * 8];
            acc[ot] = __builtin_amdgcn_mfma_f32_16x16x32_bf16(ah0, bh, acc[ot], 0, 0, 0);
            acc[ot] = __builtin_amdgcn_mfma_f32_16x16x32_bf16(al0, bh, acc[ot], 0, 0, 0);
            acc[ot] = __builtin_amdgcn_mfma_f32_16x16x32_bf16(ah0, bl, acc[ot], 0, 0, 0);
        }
    }

    if (MODE == 0) {
        #pragma unroll
        for (int ot = 0; ot < 4; ++ot) {
            int lc = ot * 16 + m;
            int col = colh * 64 + lc;
            float sc = s_s[lc], sh = s_t[lc];
            #pragma unroll
            for (int r = 0; r < 4; ++r) {
                size_t row = r0 + q * 4 + r;
                float val = fmaxf(acc[ot][r] * sc + sh, 0.0f);
                __bf16 h = (__bf16)val;
                outh[row * 128 + col] = h;
                outl[row * 128 + col] = (__bf16)(val - (float)h);
            }
        }
    } else {
        const int bidx = (int)(row0 >> 12);
        const int nbase = (int)(row0 & 4095);
        for (int cc = 0; cc < 2; ++cc) {
            __syncthreads();
            #pragma unroll
            for (int oo = 0; oo < 2; ++oo) {
                int ot = cc * 2 + oo;
                int lc = ot * 16 + m;
                int col = colh * 64 + lc;
                float sc = s_s[lc], sh = s_t[lc];
                #pragma unroll
                for (int r = 0; r < 4; ++r) {
                    int lrow = wave * 16 + q * 4 + r;
                    size_t row = row0 + lrow;
                    float val = acc[ot][r] * sc + sh;
                    val += (float)skiph[row * 128 + col] + (float)skipl[row * 128 + col];
                    val = fmaxf(val, 0.0f);
                    tile[oo * 16 + m][lrow] = val;
                }
            }
            __syncthreads();
            for (int c2 = tid >> 7; c2 < 32; c2 += 4) {
                int nn_ = tid & 127;
                outf[((size_t)bidx * 128 + colh * 64 + cc * 32 + c2) * NN + nbase + nn_]
                    = tile[c2][nn_];
            }
        }
    }
    #undef WSTB
}

extern "C" void kernel_launch(void* const* d_in, const int* in_sizes, int n_in,
                              void* d_out, int out_size, void* d_ws, size_t ws_size,
                              hipStream_t stream) {
    const float* xyz1    = (const float*)d_in[0];
    const float* xyz2    = (const float*)d_in[1];
    const float* points1 = (const float*)d_in[2];
    const float* points2 = (const float*)d_in[3];
    const float* fuse_w  = (const float*)d_in[4];
    const float* fuse_b  = (const float*)d_in[5];
    const float* fuse_g  = (const float*)d_in[6];
    const float* fuse_bt = (const float*)d_in[7];
    const float* fuse_m  = (const float*)d_in[8];
    const float* fuse_v  = (const float*)d_in[9];
    const float* c1_w    = (const float*)d_in[10];
    const float* c1_b    = (const float*)d_in[11];
    const float* bn1_g   = (const float*)d_in[12];
    const float* bn1_b   = (const float*)d_in[13];
    const float* bn1_m   = (const float*)d_in[14];
    const float* bn1_v   = (const float*)d_in[15];
    const float* c2_w    = (const float*)d_in[16];
    const float* c2_b    = (const float*)d_in[17];
    const float* bn2_g   = (const float*)d_in[18];
    const float* bn2_b   = (const float*)d_in[19];
    const float* bn2_m   = (const float*)d_in[20];
    const float* bn2_v   = (const float*)d_in[21];

    char* ws = (char*)d_ws;
    int*    idx4 = (int*)(ws);                      // 1 MB
    float*  w4   = (float*)(ws + 1048576);          // 1 MB
    float*  p2t  = (float*)(ws + 2097152);          // 16.78 MB
    __bf16* Y0h  = (__bf16*)(ws + 119537664);       // 16 MB
    __bf16* Y0l  = (__bf16*)(ws + 136314880);       // 16 MB
    __bf16* Hh   = (__bf16*)(ws + 153092096);       // 16 MB
    __bf16* Hl   = (__bf16*)(ws + 169869312);       // 16 MB
    __bf16* Whf  = (__bf16*)(ws + 186646528);       // 96 KB
    __bf16* Wlf  = (__bf16*)(ws + 186744832);       // 96 KB
    __bf16* Wh1  = (__bf16*)(ws + 186843136);       // 32 KB
    __bf16* Wl1  = (__bf16*)(ws + 186875904);       // 32 KB
    __bf16* Wh2  = (__bf16*)(ws + 186908672);       // 32 KB
    __bf16* Wl2  = (__bf16*)(ws + 186941440);       // 32 KB

    // knn partials (KCH=16 -> 16.78 MB each), in the former-X region.
    float4* pd4 = (float4*)(ws + 18874368);
    int4*   pi4 = (int4*)(ws + 18874368 + 16777216);

    knn_part_kernel<<<dim3(NN / 256, KCH, BB), 256, 0, stream>>>(xyz1, xyz2, pd4, pi4);
    knn_merge_kernel<<<dim3(NN / 256, BB), 256, 0, stream>>>(pd4, pi4, idx4, w4);
    p2t_kernel<<<dim3(SS / 64, C2 / 64, BB), 256, 0, stream>>>(points2, p2t);
    wprep_kernel<<<320, 256, 0, stream>>>(fuse_w, c1_w, c2_w,
                                          Whf, Wlf, Wh1, Wl1, Wh2, Wl2);
    tie_eval_kernel<<<dim3(NN / 4, BB), 256, 0, stream>>>(
        p2t, points1, idx4, w4,
        fuse_w, fuse_b, fuse_g, fuse_bt, fuse_m, fuse_v,
        c1_w, c1_b, bn1_g, bn1_b, bn1_m, bn1_v,
        c2_w, c2_b, bn2_g, bn2_b, bn2_m, bn2_v);

    const int gblocks = (BB * NN) / 128;   // 512
    gemm1f_kernel<<<gblocks, 512, 0, stream>>>(
        points1, p2t, idx4, w4, Whf, Wlf,
        fuse_b, fuse_g, fuse_bt, fuse_m, fuse_v, Y0h, Y0l);
    gemm_bn_kernel<CO, 0><<<1024, 512, 0, stream>>>(
        Y0h, Y0l, Wh1, Wl1, c1_b, bn1_g, bn1_b, bn1_m, bn1_v,
        nullptr, nullptr, Hh, Hl, nullptr);
    gemm_bn_kernel<CO, 1><<<1024, 512, 0, stream>>>(
        Hh, Hl, Wh2, Wl2, c2_b, bn2_g, bn2_b, bn2_m, bn2_v,
        Y0h, Y0l, nullptr, nullptr, (float*)d_out);
}

// Round 20
// 308.783 us; speedup vs baseline: 1.2831x; 1.0114x over previous
//
#include <hip/hip_runtime.h>
#include <hip/hip_bf16.h>

#define BB 16
#define NN 4096
#define SS 1024
#define C1 128
#define C2 256
#define CIN 384
#define CO 128

#define KCH 16           // knn S-chunks
#define SCH (SS / KCH)   // 64 points per chunk

typedef __bf16 bf16x8 __attribute__((ext_vector_type(8)));
typedef float f32x4 __attribute__((ext_vector_type(4)));

// ------- Kernel 1a: partial 3-NN scan over one S-chunk ---------------------
// FROZEN ARITHMETIC: distance expr + insertion chain byte-identical to the
// r12-passing scan; only the loop range is per-chunk.
__global__ __launch_bounds__(256) void knn_part_kernel(
    const float* __restrict__ xyz1, const float* __restrict__ xyz2,
    float4* __restrict__ pd4, int4* __restrict__ pi4)
{
    __shared__ float4 pts[SCH];   // 1 KB
    const int b = blockIdx.z;
    const int ch = blockIdx.y;
    const float* p2 = xyz2 + ((size_t)b * SS + (size_t)ch * SCH) * 3;
    for (int i = threadIdx.x; i < SCH; i += 256) {
        float x = p2[i * 3 + 0], y = p2[i * 3 + 1], z = p2[i * 3 + 2];
        pts[i] = make_float4(x, y, z, x * x + y * y + z * z);
    }
    __syncthreads();

    const int n = blockIdx.x * 256 + threadIdx.x;
    const float* p1 = xyz1 + ((size_t)b * NN + n) * 3;
    const float x = p1[0], y = p1[1], z = p1[2];
    const float s1 = x * x + y * y + z * z;

    float d0 = 3.4e38f, d1 = 3.4e38f, d2 = 3.4e38f, d3 = 3.4e38f;
    int i0 = 0, i1 = 0, i2 = 0, i3 = 0;
    const int sbase = ch * SCH;
    #pragma unroll 4
    for (int sl = 0; sl < SCH; ++sl) {
        float4 p = pts[sl];
        float d = s1 + p.w - 2.0f * (x * p.x + y * p.y + z * p.z);
        int s = sbase + sl;
        bool lt0 = d < d0, lt1 = d < d1, lt2 = d < d2, lt3 = d < d3;
        float nd3 = lt2 ? d2 : (lt3 ? d : d3); int ni3 = lt2 ? i2 : (lt3 ? s : i3);
        float nd2 = lt1 ? d1 : (lt2 ? d : d2); int ni2 = lt1 ? i1 : (lt2 ? s : i2);
        float nd1 = lt0 ? d0 : (lt1 ? d : d1); int ni1 = lt0 ? i0 : (lt1 ? s : i1);
        d0 = lt0 ? d : d0;                     i0 = lt0 ? s : i0;
        d1 = nd1; i1 = ni1; d2 = nd2; i2 = ni2; d3 = nd3; i3 = ni3;
    }
    size_t o = ((size_t)b * NN + n) * KCH + ch;
    pd4[o] = make_float4(d0, d1, d2, d3);
    pi4[o] = make_int4(i0, i1, i2, i3);
}

// ------- Kernel 1b: merge per-chunk top-4 -> global top-4 + weights --------
__global__ __launch_bounds__(256) void knn_merge_kernel(
    const float4* __restrict__ pd4, const int4* __restrict__ pi4,
    int* __restrict__ idx4, float* __restrict__ w4)
{
    const int n = blockIdx.x * 256 + threadIdx.x;
    const int b = blockIdx.y;
    const size_t o = ((size_t)b * NN + n) * KCH;

    float d0 = 3.4e38f, d1 = 3.4e38f, d2 = 3.4e38f, d3 = 3.4e38f;
    int i0 = 0, i1 = 0, i2 = 0, i3 = 0;
    #pragma unroll
    for (int ch = 0; ch < KCH; ++ch) {
        float4 pd = pd4[o + ch];
        int4 pi = pi4[o + ch];
        float cd[4] = { pd.x, pd.y, pd.z, pd.w };
        int   ci[4] = { pi.x, pi.y, pi.z, pi.w };
        #pragma unroll
        for (int k = 0; k < 4; ++k) {
            float d = cd[k]; int s = ci[k];
            bool lt0 = d < d0, lt1 = d < d1, lt2 = d < d2, lt3 = d < d3;
            float nd3 = lt2 ? d2 : (lt3 ? d : d3); int ni3 = lt2 ? i2 : (lt3 ? s : i3);
            float nd2 = lt1 ? d1 : (lt2 ? d : d2); int ni2 = lt1 ? i1 : (lt2 ? s : i2);
            float nd1 = lt0 ? d0 : (lt1 ? d : d1); int ni1 = lt0 ? i0 : (lt1 ? s : i1);
            d0 = lt0 ? d : d0;                     i0 = lt0 ? s : i0;
            d1 = nd1; i1 = ni1; d2 = nd2; i2 = ni2; d3 = nd3; i3 = ni3;
        }
    }
    float r0 = 1.0f / (d0 + 1e-8f);
    float r1 = 1.0f / (d1 + 1e-8f);
    float r2 = 1.0f / (d2 + 1e-8f);
    float rs = r0 + r1 + r2;
    bool tie = (d2 == d3);
    size_t base = ((size_t)b * NN + n) * 4;
    idx4[base + 0] = i0; idx4[base + 1] = i1;
    idx4[base + 2] = i2; idx4[base + 3] = i3;
    w4[base + 0] = r0 / rs; w4[base + 1] = r1 / rs;
    w4[base + 2] = r2 / rs; w4[base + 3] = tie ? -1.0f : 0.0f;
}

// ---------------- Kernel 2: transpose points2 f32[C2,S] -> f32[S,C2] -------
__global__ __launch_bounds__(256) void p2t_kernel(
    const float* __restrict__ p2, float* __restrict__ p2t)
{
    __shared__ float tile[64][65];
    const int b = blockIdx.z;
    const int s0 = blockIdx.x * 64, c0 = blockIdx.y * 64;
    for (int i = threadIdx.x; i < 64 * 64; i += 256) {
        int s = i & 63, c = i >> 6;
        tile[c][s] = p2[((size_t)b * C2 + c0 + c) * SS + s0 + s];
    }
    __syncthreads();
    for (int i = threadIdx.x; i < 64 * 64; i += 256) {
        int c = i & 63, s = i >> 6;
        p2t[((size_t)b * SS + s0 + s) * C2 + c0 + c] = tile[c][s];
    }
}

// ------- Kernel 2c: split conv weights f32 -> bf16 hi/lo planes (once) -----
__global__ __launch_bounds__(256) void wprep_kernel(
    const float* __restrict__ fw, const float* __restrict__ w1,
    const float* __restrict__ w2,
    __bf16* __restrict__ Whf, __bf16* __restrict__ Wlf,
    __bf16* __restrict__ Wh1, __bf16* __restrict__ Wl1,
    __bf16* __restrict__ Wh2, __bf16* __restrict__ Wl2)
{
    int t = blockIdx.x * 256 + threadIdx.x;
    float v; __bf16 *oh, *ol; int idx;
    if (t < 49152)      { idx = t;         v = fw[idx]; oh = Whf; ol = Wlf; }
    else if (t < 65536) { idx = t - 49152; v = w1[idx]; oh = Wh1; ol = Wl1; }
    else                { idx = t - 65536; v = w2[idx]; oh = Wh2; ol = Wl2; }
    __bf16 h = (__bf16)v;
    oh[idx] = h; ol[idx] = (__bf16)(v - (float)h);
}

// ------- Kernel 2b: tie resolver (unchanged logic from r12) ----------------
__global__ __launch_bounds__(256) void tie_eval_kernel(
    const float* __restrict__ p2t, const float* __restrict__ points1,
    const int* __restrict__ idx4, float* __restrict__ w4,
    const float* __restrict__ fw, const float* __restrict__ fb,
    const float* __restrict__ fg, const float* __restrict__ fbt,
    const float* __restrict__ fm, const float* __restrict__ fv,
    const float* __restrict__ w1m, const float* __restrict__ b1,
    const float* __restrict__ g1, const float* __restrict__ bt1,
    const float* __restrict__ m1, const float* __restrict__ v1,
    const float* __restrict__ w2m, const float* __restrict__ b2,
    const float* __restrict__ g2, const float* __restrict__ bt2,
    const float* __restrict__ m2, const float* __restrict__ v2)
{
    __shared__ float Xs[4][2][CIN];
    __shared__ float XT[4][2][CO];
    __shared__ float Hs[4][2][CO];
    const int wave = threadIdx.x >> 6, lane = threadIdx.x & 63;
    const int n = blockIdx.x * 4 + wave;
    const int b = blockIdx.y;
    const size_t base = ((size_t)b * NN + n) * 4;
    if (w4[base + 3] != -1.0f) return;

    const int i0 = idx4[base + 0], i1 = idx4[base + 1];
    const int i2 = idx4[base + 2], i3 = idx4[base + 3];
    const float w0 = w4[base + 0], w1 = w4[base + 1], w2 = w4[base + 2];
    const float* P = p2t + (size_t)b * SS * C2;

    for (int c = lane; c < C1; c += 64) {
        float v = points1[((size_t)b * C1 + c) * NN + n];
        Xs[wave][0][c] = v; Xs[wave][1][c] = v;
    }
    for (int c = lane; c < C2; c += 64) {
        float f0 = P[(size_t)i0 * C2 + c], f1 = P[(size_t)i1 * C2 + c];
        float f2 = P[(size_t)i2 * C2 + c], f3 = P[(size_t)i3 * C2 + c];
        float bs = w0 * f0 + w1 * f1;
        Xs[wave][0][C1 + c] = bs + w2 * f2;
        Xs[wave][1][C1 + c] = bs + w2 * f3;
    }
    #pragma unroll
    for (int k = 0; k < 2; ++k) {
        int oc = lane + 64 * k;
        float alo = fb[oc], ahi = fb[oc];
        for (int c = 0; c < CIN; ++c) {
            float wv = fw[(size_t)oc * CIN + c];
            alo += wv * Xs[wave][0][c];
            ahi += wv * Xs[wave][1][c];
        }
        float s = fg[oc] * (1.0f / sqrtf(fv[oc] + 1e-5f));
        XT[wave][0][oc] = fmaxf(s * (alo - fm[oc]) + fbt[oc], 0.0f);
        XT[wave][1][oc] = fmaxf(s * (ahi - fm[oc]) + fbt[oc], 0.0f);
    }
    #pragma unroll
    for (int k = 0; k < 2; ++k) {
        int oc = lane + 64 * k;
        float alo = b1[oc], ahi = b1[oc];
        for (int c = 0; c < CO; ++c) {
            float wv = w1m[(size_t)oc * CO + c];
            alo += wv * XT[wave][0][c];
            ahi += wv * XT[wave][1][c];
        }
        float s = g1[oc] * (1.0f / sqrtf(v1[oc] + 1e-5f));
        Hs[wave][0][oc] = fmaxf(s * (alo - m1[oc]) + bt1[oc], 0.0f);
        Hs[wave][1][oc] = fmaxf(s * (ahi - m1[oc]) + bt1[oc], 0.0f);
    }
    float e = 0.0f;
    #pragma unroll
    for (int k = 0; k < 2; ++k) {
        int oc = lane + 64 * k;
        float alo = b2[oc], ahi = b2[oc];
        for (int c = 0; c < CO; ++c) {
            float wv = w2m[(size_t)oc * CO + c];
            alo += wv * Hs[wave][0][c];
            ahi += wv * Hs[wave][1][c];
        }
        float s = g2[oc] * (1.0f / sqrtf(v2[oc] + 1e-5f));
        float olo = fmaxf(s * (alo - m2[oc]) + bt2[oc] + XT[wave][0][oc], 0.0f);
        float ohi = fmaxf(s * (ahi - m2[oc]) + bt2[oc] + XT[wave][1][oc], 0.0f);
        e = fmaxf(e, fabsf(olo - ohi));
    }
    for (int off = 32; off; off >>= 1) e = fmaxf(e, __shfl_xor(e, off));
    if (lane == 0) {
        if (e > 0.085f) { w4[base + 3] = 0.0f; }
        else { w4[base + 2] = 0.5f * w2; w4[base + 3] = 0.5f * w2; }
    }
}

// ------- Kernel 4: FUSED GEMM1, BK=64 (6 phases instead of 12) -------------
// r15 post-mortem: 12 barrier-drained phases are the cost; each drain
// serializes that phase's 8 gather loads. BK=64 halves the drain count and
// issues TWO K-steps' independent loads per phase (2x MLP per drain).
// Same 2-barrier template as the r9-measured version; per-element MFMA
// accumulation order identical (kk then kk+32) -> bit-identical Y0.
__global__ __launch_bounds__(512) void gemm1f_kernel(
    const float* __restrict__ points1, const float* __restrict__ p2t,
    const int* __restrict__ idx4, const float* __restrict__ w4,
    const __bf16* __restrict__ Wh, const __bf16* __restrict__ Wl,
    const float* __restrict__ cb,  const float* __restrict__ gg,
    const float* __restrict__ bbta, const float* __restrict__ mm,
    const float* __restrict__ vv,
    __bf16* __restrict__ outh, __bf16* __restrict__ outl)
{
    #define WST1 72   // LDS K-stride (64 + 8 pad); lane-m stride 36dw -> 2-way (free)
    __shared__ __attribute__((aligned(16))) __bf16 wls_h[128 * WST1]; // 18 KB
    __shared__ __attribute__((aligned(16))) __bf16 wls_l[128 * WST1]; // 18 KB
    __shared__ float s_s[128], s_t[128];
    const int tid = threadIdx.x;
    if (tid < 128) {
        float s = gg[tid] * (1.0f / sqrtf(vv[tid] + 1e-5f));
        float t = (cb[tid] - mm[tid]) * s + bbta[tid];
        s_s[tid] = s; s_t[tid] = t;
    }
    const int bid = (blockIdx.x & 7) * 64 + (blockIdx.x >> 3);  // bijective, 512=8*64
    const int b = bid >> 5;                 // 32 row-blocks per batch
    const int nbase = (bid & 31) * 128;
    const int wave = tid >> 6, lane = tid & 63;
    const int m = lane & 15, q = lane >> 4;

    // one 16-row tile per wave
    const size_t pa = (size_t)b * NN + nbase + wave * 16 + m;
    const int4   ia4 = *(const int4*)&idx4[pa * 4];
    const float4 wa4 = *(const float4*)&w4[pa * 4];
    const float* P = p2t + (size_t)b * SS * C2;

    f32x4 acc[8] = {};
    const int wrow = tid >> 2, wseg = tid & 3;   // 4 threads per W row

    for (int kk = 0; kk < CIN; kk += 64) {
        __syncthreads();
        {   // stage 64-wide Wh/Wl strip: each thread 16 elems per plane
            size_t g = (size_t)wrow * CIN + kk + wseg * 16;
            int lo = wrow * WST1 + wseg * 16;
            *(uint4*)&wls_h[lo]     = *(const uint4*)&Wh[g];
            *(uint4*)&wls_h[lo + 8] = *(const uint4*)&Wh[g + 8];
            *(uint4*)&wls_l[lo]     = *(const uint4*)&Wl[g];
            *(uint4*)&wls_l[lo + 8] = *(const uint4*)&Wl[g + 8];
        }
        __syncthreads();

        bf16x8 a0h, a0l, a1h, a1l;   // sub-steps kk and kk+32
        if (kk < C1) {
            // both sub-steps on the points1 path (C1=128 = 2*64)
            const float* p1 = points1 + ((size_t)b * C1 + kk + q * 8) * NN
                            + nbase + wave * 16 + m;
            const float* p1b = p1 + (size_t)32 * NN;
            #pragma unroll
            for (int j = 0; j < 8; ++j) {
                float v = p1[(size_t)j * NN];
                __bf16 h = (__bf16)v;
                a0h[j] = h; a0l[j] = (__bf16)(v - (float)h);
            }
            #pragma unroll
            for (int j = 0; j < 8; ++j) {
                float v = p1b[(size_t)j * NN];
                __bf16 h = (__bf16)v;
                a1h[j] = h; a1l[j] = (__bf16)(v - (float)h);
            }
        } else {
            // both sub-steps on the gather path; 16 independent float4 loads
            const int c0 = kk - C1 + q * 8;
            const float* g0 = P + (size_t)ia4.x * C2 + c0;
            const float* g1 = P + (size_t)ia4.y * C2 + c0;
            const float* g2 = P + (size_t)ia4.z * C2 + c0;
            const float* g3 = P + (size_t)ia4.w * C2 + c0;
            #pragma unroll
            for (int half = 0; half < 2; ++half) {   // 0 -> kk, 1 -> kk+32
                const int co = half * 32;
                #pragma unroll
                for (int hh = 0; hh < 2; ++hh) {
                    float4 f0 = *(const float4*)(g0 + co + hh * 4);
                    float4 f1 = *(const float4*)(g1 + co + hh * 4);
                    float4 f2 = *(const float4*)(g2 + co + hh * 4);
                    float4 f3 = *(const float4*)(g3 + co + hh * 4);
                    float v0 = wa4.x * f0.x + wa4.y * f1.x + wa4.z * f2.x + wa4.w * f3.x;
                    float v1 = wa4.x * f0.y + wa4.y * f1.y + wa4.z * f2.y + wa4.w * f3.y;
                    float v2 = wa4.x * f0.z + wa4.y * f1.z + wa4.z * f2.z + wa4.w * f3.z;
                    float v3 = wa4.x * f0.w + wa4.y * f1.w + wa4.z * f2.w + wa4.w * f3.w;
                    __bf16 h0 = (__bf16)v0, h1 = (__bf16)v1;
                    __bf16 h2 = (__bf16)v2, h3 = (__bf16)v3;
                    if (half == 0) {
                        a0h[hh * 4 + 0] = h0; a0l[hh * 4 + 0] = (__bf16)(v0 - (float)h0);
                        a0h[hh * 4 + 1] = h1; a0l[hh * 4 + 1] = (__bf16)(v1 - (float)h1);
                        a0h[hh * 4 + 2] = h2; a0l[hh * 4 + 2] = (__bf16)(v2 - (float)h2);
                        a0h[hh * 4 + 3] = h3; a0l[hh * 4 + 3] = (__bf16)(v3 - (float)h3);
                    } else {
                        a1h[hh * 4 + 0] = h0; a1l[hh * 4 + 0] = (__bf16)(v0 - (float)h0);
                        a1h[hh * 4 + 1] = h1; a1l[hh * 4 + 1] = (__bf16)(v1 - (float)h1);
                        a1h[hh * 4 + 2] = h2; a1l[hh * 4 + 2] = (__bf16)(v2 - (float)h2);
                        a1h[hh * 4 + 3] = h3; a1l[hh * 4 + 3] = (__bf16)(v3 - (float)h3);
                    }
                }
            }
        }

        // sub-step kk (same 3-MFMA chain per acc element as r9)
        #pragma unroll
        for (int ot = 0; ot < 8; ++ot) {
            bf16x8 bh = *(const bf16x8*)&wls_h[(ot * 16 + m) * WST1 + q * 8];
            bf16x8 bl = *(const bf16x8*)&wls_l[(ot * 16 + m) * WST1 + q * 8];
            acc[ot] = __builtin_amdgcn_mfma_f32_16x16x32_bf16(a0h, bh, acc[ot], 0, 0, 0);
            acc[ot] = __builtin_amdgcn_mfma_f32_16x16x32_bf16(a0l, bh, acc[ot], 0, 0, 0);
            acc[ot] = __builtin_amdgcn_mfma_f32_16x16x32_bf16(a0h, bl, acc[ot], 0, 0, 0);
        }
        // sub-step kk+32
        #pragma unroll
        for (int ot = 0; ot < 8; ++ot) {
            bf16x8 bh = *(const bf16x8*)&wls_h[(ot * 16 + m) * WST1 + 32 + q * 8];
            bf16x8 bl = *(const bf16x8*)&wls_l[(ot * 16 + m) * WST1 + 32 + q * 8];
            acc[ot] = __builtin_amdgcn_mfma_f32_16x16x32_bf16(a1h, bh, acc[ot], 0, 0, 0);
            acc[ot] = __builtin_amdgcn_mfma_f32_16x16x32_bf16(a1l, bh, acc[ot], 0, 0, 0);
            acc[ot] = __builtin_amdgcn_mfma_f32_16x16x32_bf16(a1h, bl, acc[ot], 0, 0, 0);
        }
    }

    const size_t r0 = (size_t)bid * 128 + wave * 16;
    #pragma unroll
    for (int ot = 0; ot < 8; ++ot) {
        int col = ot * 16 + m;
        float sc = s_s[col], sh = s_t[col];
        #pragma unroll
        for (int r = 0; r < 4; ++r) {
            size_t row = r0 + q * 4 + r;
            float val = fmaxf(acc[ot][r] * sc + sh, 0.0f);
            __bf16 h = (__bf16)val;
            outh[row * 128 + col] = h;
            outl[row * 128 + col] = (__bf16)(val - (float)h);
        }
    }
    #undef WST1
}

// ------- Kernels 5-6: gemm_bn v3 — stage-W-once, ZERO in-loop barriers -----
// (unchanged from r15: measured pass @ total 312.3)
template<int K, int MODE>
__global__ __launch_bounds__(512) void gemm_bn_kernel(
    const __bf16* __restrict__ Ah, const __bf16* __restrict__ Al,
    const __bf16* __restrict__ Wh, const __bf16* __restrict__ Wl,
    const float* __restrict__ cb,  const float* __restrict__ gg,
    const float* __restrict__ bbta, const float* __restrict__ mm,
    const float* __restrict__ vv,
    const __bf16* __restrict__ skiph, const __bf16* __restrict__ skipl,
    __bf16* __restrict__ outh, __bf16* __restrict__ outl,
    float* __restrict__ outf)
{
    #define WSTB 136   // LDS K-stride (128 + 8 pad)
    __shared__ __attribute__((aligned(16))) __bf16 wls_h[64 * WSTB]; // 17 KB
    __shared__ __attribute__((aligned(16))) __bf16 wls_l[64 * WSTB]; // 17 KB
    __shared__ float s_s[64], s_t[64];
    __shared__ float tile[32][132];   // MODE1 transpose staging
    const int tid = threadIdx.x;

    // 1024 blocks = 512 row-blocks x 2 col-halves; XCD-chunked bijective.
    const int swz = (blockIdx.x & 7) * 128 + (blockIdx.x >> 3);
    const int colh = swz & 1;
    const int rowblk = swz >> 1;
    const size_t row0 = (size_t)rowblk * 128;

    // ---- one-time W stage: 64 cols x K, hi+lo ----
    for (int i = tid; i < 64 * (K / 8); i += 512) {
        int col = i / (K / 8), ch = i % (K / 8);
        size_t g = (size_t)(colh * 64 + col) * K + ch * 8;
        int lo = col * WSTB + ch * 8;
        *(uint4*)&wls_h[lo] = *(const uint4*)&Wh[g];
        *(uint4*)&wls_l[lo] = *(const uint4*)&Wl[g];
    }
    if (tid < 64) {
        int oc = colh * 64 + tid;
        float s = gg[oc] * (1.0f / sqrtf(vv[oc] + 1e-5f));
        s_s[tid] = s;
        s_t[tid] = (cb[oc] - mm[oc]) * s + bbta[oc];
    }
    __syncthreads();   // the only barrier before the epilogue

    const int wave = tid >> 6, lane = tid & 63;
    const int m = lane & 15, q = lane >> 4;
    const size_t r0 = row0 + wave * 16;

    f32x4 acc[4] = {};
    const __bf16* pAh = Ah + (r0 + m) * (size_t)K + q * 8;
    const __bf16* pAl = Al + (r0 + m) * (size_t)K + q * 8;

    for (int kk = 0; kk < K; kk += 32) {
        bf16x8 ah0 = *(const bf16x8*)(pAh + kk);
        bf16x8 al0 = *(const bf16x8*)(pAl + kk);
        #pragma unroll
        for (int ot = 0; ot < 4; ++ot) {
            bf16x8 bh = *(const bf16x8*)&wls_h[(ot * 16 + m) * WSTB + kk + q * 8];
            bf16x8 bl = *(const bf16x8*)&wls_l[(ot * 16 + m) * WSTB + kk + q * 8];
            acc[ot] = __builtin_amdgcn_mfma_f32_16x16x32_bf16(ah0, bh, acc[ot], 0, 0, 0);
            acc[ot] = __builtin_amdgcn_mfma_f32_16x16x32_bf16(al0, bh, acc[ot], 0, 0, 0);
            acc[ot] = __builtin_amdgcn_mfma_f32_16x16x32_bf16(ah0, bl, acc[ot], 0, 0, 0);
        }
    }

    if (MODE == 0) {
        #pragma unroll
        for (int ot = 0; ot < 4; ++ot) {
            int lc = ot * 16 + m;
            int col = colh * 64 + lc;
            float sc = s_s[lc], sh = s_t[lc];
            #pragma unroll
            for (int r = 0; r < 4; ++r) {
                size_t row = r0 + q * 4 + r;
                float val = fmaxf(acc[ot][r] * sc + sh, 0.0f);
                __bf16 h = (__bf16)val;
                outh[row * 128 + col] = h;
                outl[row * 128 + col] = (__bf16)(val - (float)h);
            }
        }
    } else {
        const int bidx = (int)(row0 >> 12);
        const int nbase = (int)(row0 & 4095);
        for (int cc = 0; cc < 2; ++cc) {
            __syncthreads();
            #pragma unroll
            for (int oo = 0; oo < 2; ++oo) {
                int ot = cc * 2 + oo;
                int lc = ot * 16 + m;
                int col = colh * 64 + lc;
                float sc = s_s[lc], sh = s_t[lc];
                #pragma unroll
                for (int r = 0; r < 4; ++r) {
                    int lrow = wave * 16 + q * 4 + r;
                    size_t row = row0 + lrow;
                    float val = acc[ot][r] * sc + sh;
                    val += (float)skiph[row * 128 + col] + (float)skipl[row * 128 + col];
                    val = fmaxf(val, 0.0f);
                    tile[oo * 16 + m][lrow] = val;
                }
            }
            __syncthreads();
            for (int c2 = tid >> 7; c2 < 32; c2 += 4) {
                int nn_ = tid & 127;
                outf[((size_t)bidx * 128 + colh * 64 + cc * 32 + c2) * NN + nbase + nn_]
                    = tile[c2][nn_];
            }
        }
    }
    #undef WSTB
}

extern "C" void kernel_launch(void* const* d_in, const int* in_sizes, int n_in,
                              void* d_out, int out_size, void* d_ws, size_t ws_size,
                              hipStream_t stream) {
    const float* xyz1    = (const float*)d_in[0];
    const float* xyz2    = (const float*)d_in[1];
    const float* points1 = (const float*)d_in[2];
    const float* points2 = (const float*)d_in[3];
    const float* fuse_w  = (const float*)d_in[4];
    const float* fuse_b  = (const float*)d_in[5];
    const float* fuse_g  = (const float*)d_in[6];
    const float* fuse_bt = (const float*)d_in[7];
    const float* fuse_m  = (const float*)d_in[8];
    const float* fuse_v  = (const float*)d_in[9];
    const float* c1_w    = (const float*)d_in[10];
    const float* c1_b    = (const float*)d_in[11];
    const float* bn1_g   = (const float*)d_in[12];
    const float* bn1_b   = (const float*)d_in[13];
    const float* bn1_m   = (const float*)d_in[14];
    const float* bn1_v   = (const float*)d_in[15];
    const float* c2_w    = (const float*)d_in[16];
    const float* c2_b    = (const float*)d_in[17];
    const float* bn2_g   = (const float*)d_in[18];
    const float* bn2_b   = (const float*)d_in[19];
    const float* bn2_m   = (const float*)d_in[20];
    const float* bn2_v   = (const float*)d_in[21];

    char* ws = (char*)d_ws;
    int*    idx4 = (int*)(ws);                      // 1 MB
    float*  w4   = (float*)(ws + 1048576);          // 1 MB
    float*  p2t  = (float*)(ws + 2097152);          // 16.78 MB
    __bf16* Y0h  = (__bf16*)(ws + 119537664);       // 16 MB
    __bf16* Y0l  = (__bf16*)(ws + 136314880);       // 16 MB
    __bf16* Hh   = (__bf16*)(ws + 153092096);       // 16 MB
    __bf16* Hl   = (__bf16*)(ws + 169869312);       // 16 MB
    __bf16* Whf  = (__bf16*)(ws + 186646528);       // 96 KB
    __bf16* Wlf  = (__bf16*)(ws + 186744832);       // 96 KB
    __bf16* Wh1  = (__bf16*)(ws + 186843136);       // 32 KB
    __bf16* Wl1  = (__bf16*)(ws + 186875904);       // 32 KB
    __bf16* Wh2  = (__bf16*)(ws + 186908672);       // 32 KB
    __bf16* Wl2  = (__bf16*)(ws + 186941440);       // 32 KB

    // knn partials (KCH=16 -> 16.78 MB each), in the former-X region.
    float4* pd4 = (float4*)(ws + 18874368);
    int4*   pi4 = (int4*)(ws + 18874368 + 16777216);

    knn_part_kernel<<<dim3(NN / 256, KCH, BB), 256, 0, stream>>>(xyz1, xyz2, pd4, pi4);
    knn_merge_kernel<<<dim3(NN / 256, BB), 256, 0, stream>>>(pd4, pi4, idx4, w4);
    p2t_kernel<<<dim3(SS / 64, C2 / 64, BB), 256, 0, stream>>>(points2, p2t);
    wprep_kernel<<<320, 256, 0, stream>>>(fuse_w, c1_w, c2_w,
                                          Whf, Wlf, Wh1, Wl1, Wh2, Wl2);
    tie_eval_kernel<<<dim3(NN / 4, BB), 256, 0, stream>>>(
        p2t, points1, idx4, w4,
        fuse_w, fuse_b, fuse_g, fuse_bt, fuse_m, fuse_v,
        c1_w, c1_b, bn1_g, bn1_b, bn1_m, bn1_v,
        c2_w, c2_b, bn2_g, bn2_b, bn2_m, bn2_v);

    const int gblocks = (BB * NN) / 128;   // 512
    gemm1f_kernel<<<gblocks, 512, 0, stream>>>(
        points1, p2t, idx4, w4, Whf, Wlf,
        fuse_b, fuse_g, fuse_bt, fuse_m, fuse_v, Y0h, Y0l);
    gemm_bn_kernel<CO, 0><<<1024, 512, 0, stream>>>(
        Y0h, Y0l, Wh1, Wl1, c1_b, bn1_g, bn1_b, bn1_m, bn1_v,
        nullptr, nullptr, Hh, Hl, nullptr);
    gemm_bn_kernel<CO, 1><<<1024, 512, 0, stream>>>(
        Hh, Hl, Wh2, Wl2, c2_b, bn2_g, bn2_b, bn2_m, bn2_v,
        Y0h, Y0l, nullptr, nullptr, (float*)d_out);
}